// Round 9
// baseline (635.535 us; speedup 1.0000x reference)
//
#include <hip/hip_runtime.h>
#include <hip/hip_bf16.h>

#define N_VOX 200000
#define KOFF 27
#define PPK 100000
#define C 64
#define BN_EPS 1e-5f

typedef __bf16 bf16x8 __attribute__((ext_vector_type(8)));
typedef __bf16 bf16x4 __attribute__((ext_vector_type(4)));
typedef float f32x4 __attribute__((ext_vector_type(4)));

// ---------------------------------------------------------------------------
// features fp32 -> bf16 (RNE), vectorized: 1 float4 in -> 4 bf16 (8B) out.
// ---------------------------------------------------------------------------
__global__ __launch_bounds__(256)
void convert_features(const float* __restrict__ f, __bf16* __restrict__ fb)
{
    const size_t total4 = (size_t)N_VOX * C / 4;
    const size_t i = (size_t)blockIdx.x * blockDim.x + threadIdx.x;
    if (i >= total4) return;
    const float4 v = ((const float4*)f)[i];
    bf16x4 o;
    o.x = (__bf16)v.x; o.y = (__bf16)v.y; o.z = (__bf16)v.z; o.w = (__bf16)v.w;
    ((bf16x4*)fb)[i] = o;
}

// ---------------------------------------------------------------------------
// weight [k][cin][cout] fp32 -> wt [k][cout][cin] bf16 (transposed).
// Fused housekeeping: zeroes histogram bins and stats (saves 2 memsets).
// ---------------------------------------------------------------------------
__global__ __launch_bounds__(256)
void convert_weight(const float* __restrict__ w, __bf16* __restrict__ wt,
                    unsigned* __restrict__ counts_or_null,
                    float* __restrict__ stats)
{
    const int k = blockIdx.x;
    const float* W = w + (size_t)k * C * C;
    __bf16* Wt = wt + (size_t)k * C * C;
    for (int idx = threadIdx.x; idx < C * C; idx += 256) {
        const int ci = idx >> 6, co = idx & 63;
        Wt[co * C + ci] = (__bf16)W[idx];
    }
    if (counts_or_null) {
        for (int i = blockIdx.x * 256 + threadIdx.x; i < N_VOX; i += KOFF * 256)
            counts_or_null[i] = 0u;
        if (blockIdx.x == 0 && threadIdx.x < 128) stats[threadIdx.x] = 0.f;
    }
}

// ===========================================================================
// Rulebook inversion (per k-chunk): histogram capturing per-pair rank ->
// exclusive scan. Slot add (rank + offsets[out]) fused into conv_scatter as
// a plain gather (atomics stay in latency-tolerant streaming passes).
// ===========================================================================
__global__ __launch_bounds__(256)
void hist_kernel(const int* __restrict__ out_idx, unsigned* __restrict__ counts,
                 unsigned* __restrict__ rank, int k0, int npair)
{
    const int i = blockIdx.x * 256 + threadIdx.x;
    if (i < npair) {
        const int o = out_idx[(size_t)k0 * PPK + i];
        rank[i] = atomicAdd(&counts[o], 1u);   // rank within voxel (this chunk)
    }
}

// exclusive scan of counts[200000] -> offsets; re-zeroes counts for next chunk.
__global__ __launch_bounds__(256)
void scan1(unsigned* __restrict__ counts, unsigned* __restrict__ offsets,
           unsigned* __restrict__ bsums)
{
    __shared__ unsigned sdata[256];
    const int t = threadIdx.x;
    const int base = blockIdx.x * 1024 + t * 4;
    unsigned v[4]; unsigned s = 0;
#pragma unroll
    for (int u = 0; u < 4; ++u) {
        const bool ok = (base + u < N_VOX);
        v[u] = ok ? counts[base + u] : 0u;
        if (ok) counts[base + u] = 0u;
        s += v[u];
    }
    sdata[t] = s;
    __syncthreads();
    for (int off = 1; off < 256; off <<= 1) {
        const unsigned add = (t >= off) ? sdata[t - off] : 0u;
        __syncthreads();
        sdata[t] += add;
        __syncthreads();
    }
    const unsigned incl = sdata[t];
    unsigned run = incl - s;          // exclusive prefix for this thread
    if (t == 255) bsums[blockIdx.x] = incl;
#pragma unroll
    for (int u = 0; u < 4; ++u) {
        if (base + u < N_VOX) offsets[base + u] = run;
        run += v[u];
    }
}

// Merged scan2+scan3: each block redundantly sums bsums[0..q-1] (L2-hot).
__global__ __launch_bounds__(256)
void scan23(unsigned* __restrict__ offsets, const unsigned* __restrict__ bsums)
{
    const int i = blockIdx.x * 256 + threadIdx.x;
    const int q = blockIdx.x >> 2;
    const int lane = threadIdx.x & 63;
    unsigned s = 0;
    for (int j = lane; j < q; j += 64) s += bsums[j];
#pragma unroll
    for (int m = 1; m < 64; m <<= 1) s += __shfl_xor(s, m, 64);
    if (i < N_VOX) offsets[i] += s;
}

// ===========================================================================
// Conv via MFMA, scatter partial rows (bf16) to out-sorted slots. NO atomics:
// slot = rank[pair] + offsets[out], issued at kernel start. 32 KB XOR-
// swizzled LDS A-tile, 0 bank conflicts. Runs at the random-128B-write
// HBM rate (~2.8 TB/s) — near its structural ceiling.
// Partial row layout c' = m16*4 + nt (true channel c = nt*16 + m16).
// ===========================================================================
__global__ __launch_bounds__(256)
void conv_scatter(const __bf16* __restrict__ featb, const __bf16* __restrict__ wtb,
                  const int* __restrict__ in_idx, const int* __restrict__ out_idx,
                  const unsigned* __restrict__ rank, const unsigned* __restrict__ offsets,
                  __bf16* __restrict__ partial, int k0)
{
    constexpr int TP = 256;       // pairs per tile
    __shared__ __bf16 sA[TP * 64];   // 32 KB exactly

    const int kloc = blockIdx.y;
    const int k = k0 + kloc;
    const int tile_base = blockIdx.x * TP;
    const int t = threadIdx.x;
    const int lane = t & 63;
    const int wave = t >> 6;
    const int m16 = lane & 15;    // A: pair-row in 16; B: cout; C/D: col
    const int quad = lane >> 4;   // 0..3

    // this thread's pair slot (consumed via shfl at the end)
    unsigned my_slot = 0u;
    {
        const int pair = tile_base + t;
        if (pair < PPK) {
            const int o = out_idx[(size_t)k * PPK + pair];
            my_slot = rank[(size_t)kloc * PPK + pair] + offsets[o];
        }
    }

    // B fragments from Wt[k][cout][cin]
    const __bf16* Wt = wtb + (size_t)k * C * C;
    bf16x8 bfrag[4][2];
#pragma unroll
    for (int nt = 0; nt < 4; ++nt)
#pragma unroll
        for (int kc = 0; kc < 2; ++kc)
            bfrag[nt][kc] = *(const bf16x8*)(Wt + (nt * 16 + m16) * C + kc * 32 + quad * 8);

    // stage gathered A rows: thread t loads row (t>>3)+32*it, 16B chunk (t&7),
    // stored at swizzled chunk (c8 ^ (r&7)).
    const int c8 = t & 7;
    const int r0 = t >> 3;
#pragma unroll
    for (int it = 0; it < 8; ++it) {
        const int r = r0 + it * 32;               // r&7 == r0&7
        const int pair = tile_base + r;
        const int row = (pair < PPK) ? in_idx[(size_t)k * PPK + pair] : 0;
        const float4 v = *(const float4*)(featb + (size_t)row * C + c8 * 8);
        *(float4*)(sA + r * 64 + ((c8 ^ (r0 & 7)) << 3)) = v;
    }
    __syncthreads();

    // MFMA: wave owns pairs [wave*64, wave*64+64). Read chunk (kc*4+quad)^(m16&7).
    f32x4 acc[4][4] = {};
    const int mbase = wave * 64;
#pragma unroll
    for (int kc = 0; kc < 2; ++kc) {
        bf16x8 afrag[4];
#pragma unroll
        for (int mt = 0; mt < 4; ++mt)
            afrag[mt] = *(const bf16x8*)(sA + (mbase + mt * 16 + m16) * 64
                                         + ((((kc << 2) | quad) ^ (m16 & 7)) << 3));
#pragma unroll
        for (int nt = 0; nt < 4; ++nt)
#pragma unroll
            for (int mt = 0; mt < 4; ++mt)
                acc[mt][nt] = __builtin_amdgcn_mfma_f32_16x16x32_bf16(
                    afrag[mt], bfrag[nt][kc], acc[mt][nt], 0, 0, 0);
    }

    // scatter partial rows: per (mt,reg) row, 16 lanes of a quad write the
    // full 128B bf16 row (8B per lane) at its out-sorted slot.
#pragma unroll
    for (int mt = 0; mt < 4; ++mt) {
#pragma unroll
        for (int reg = 0; reg < 4; ++reg) {
            const int rloc = mt * 16 + quad * 4 + reg;       // row within wave stripe
            const unsigned s = __shfl(my_slot, rloc, 64);
            const int pair = tile_base + mbase + rloc;
            if (pair < PPK) {
                bf16x4 pv;
                pv.x = (__bf16)acc[mt][0][reg];
                pv.y = (__bf16)acc[mt][1][reg];
                pv.z = (__bf16)acc[mt][2][reg];
                pv.w = (__bf16)acc[mt][3][reg];
                *(bf16x4*)(partial + (size_t)s * C + (m16 << 2)) = pv;
            }
        }
    }
}

// ---------------------------------------------------------------------------
// Reduce: one out row per WAVE, grid-stride, SOFTWARE-PIPELINED depth 2.
// Rounds 7/8 nulls (width x2, grid x2, occ 38->61%, dur flat 108us) isolate
// per-wave MLP=1 as the limiter: the serial chain offsets->slots->reduce->
// store never overlaps voxels. Now: voxel n+1's slot vector and voxel n+2's
// offsets issue BEFORE voxel n's shuffle-reduce, hiding ~600cy HBM latency
// under ~400cy compute. Lane map unchanged: e = lane>>3 slots, j = lane&7
// channel-8 group, cmap p=8j+i -> true c = (p&3)*16+(p>>2); shfl_xor(8,16,32);
// last chunk folds per-channel stats.
// ---------------------------------------------------------------------------
__global__ __launch_bounds__(256)
void reduce_kernel(const __bf16* __restrict__ partial,
                   const unsigned* __restrict__ offsets,
                   float* __restrict__ out, float* __restrict__ stats,
                   const int first, const int last, const unsigned np)
{
    __shared__ float sstat[512];
    const int wave = threadIdx.x >> 6;
    const int lane = threadIdx.x & 63;
    const int e = lane >> 3;      // 0..7: slot sub-lane
    const int j = lane & 7;       // channel-8 group
    const int stride = gridDim.x * 4;
    const int w0 = blockIdx.x * 4 + wave;

    float tacc[8] = {0.f, 0.f, 0.f, 0.f, 0.f, 0.f, 0.f, 0.f};
    float qacc[8] = {0.f, 0.f, 0.f, 0.f, 0.f, 0.f, 0.f, 0.f};
    int cmap[8];
#pragma unroll
    for (int i = 0; i < 8; ++i) {
        const int p = j * 8 + i;
        cmap[i] = (p & 3) * 16 + (p >> 2);
    }

    // ---- pipeline prologue ----
    int o0 = w0;
    unsigned beg0 = 0, end0 = 0;
    bf16x8 v0 = {};
    if (o0 < N_VOX) {
        beg0 = offsets[o0];
        end0 = (o0 + 1 < N_VOX) ? offsets[o0 + 1] : np;
        if (beg0 + e < end0)
            v0 = *(const bf16x8*)(partial + (size_t)(beg0 + e) * C + (j << 3));
    }
    int o1 = w0 + stride;
    unsigned beg1 = 0, end1 = 0;
    if (o1 < N_VOX) {
        beg1 = offsets[o1];
        end1 = (o1 + 1 < N_VOX) ? offsets[o1 + 1] : np;
    }

    while (o0 < N_VOX) {
        // issue NEXT voxel's slot vector load early (overlaps this voxel's work)
        bf16x8 v1 = {};
        if (o1 < N_VOX && beg1 + e < end1)
            v1 = *(const bf16x8*)(partial + (size_t)(beg1 + e) * C + (j << 3));
        // issue offsets for voxel n+2
        const int o2 = o1 + stride;
        unsigned beg2 = 0, end2 = 0;
        if (o2 < N_VOX) {
            beg2 = offsets[o2];
            end2 = (o2 + 1 < N_VOX) ? offsets[o2 + 1] : np;
        }
        // prefetch RMW operands for the current voxel
        float* orow = out + (size_t)o0 * C;
        float prev[8];
        if (!first && e == 0) {
#pragma unroll
            for (int i = 0; i < 8; ++i) prev[i] = orow[cmap[i]];
        }
        // accumulate current voxel (first 8 slots already in v0; rare tail loop)
        float a[8];
#pragma unroll
        for (int i = 0; i < 8; ++i) a[i] = (float)v0[i];
        for (unsigned s = beg0 + 8 + e; s < end0; s += 8) {
            const bf16x8 v = *(const bf16x8*)(partial + (size_t)s * C + (j << 3));
#pragma unroll
            for (int i = 0; i < 8; ++i) a[i] += (float)v[i];
        }
#pragma unroll
        for (int m = 8; m <= 32; m <<= 1)
#pragma unroll
            for (int i = 0; i < 8; ++i) a[i] += __shfl_xor(a[i], m, 64);
        if (e == 0) {
#pragma unroll
            for (int i = 0; i < 8; ++i) {
                float v = a[i];
                if (!first) v += prev[i];
                orow[cmap[i]] = v;
                if (last) { tacc[i] += v; qacc[i] += v * v; }
            }
        }
        // shift pipeline
        o0 = o1; beg0 = beg1; end0 = end1; v0 = v1;
        o1 = o2; beg1 = beg2; end1 = end2;
    }

    if (last) {
        if (e == 0) {
#pragma unroll
            for (int i = 0; i < 8; ++i) {
                sstat[wave * 64 + cmap[i]]       = tacc[i];
                sstat[256 + wave * 64 + cmap[i]] = qacc[i];
            }
        }
        __syncthreads();
        const int t = threadIdx.x;
        if (t < 64) {
            const float ss = sstat[t] + sstat[64 + t] + sstat[128 + t] + sstat[192 + t];
            const float qq = sstat[256 + t] + sstat[320 + t] + sstat[384 + t] + sstat[448 + t];
            unsafeAtomicAdd(&stats[t], ss);
            unsafeAtomicAdd(&stats[64 + t], qq);
        }
    }
}

// ===========================================================================
// Fallback conv (proven): atomic scatter-add + separate stats. Used only if
// workspace is too small for the sorted-partial path.
// ===========================================================================
__global__ __launch_bounds__(256)
void conv_mfma(const __bf16* __restrict__ featb, const __bf16* __restrict__ wtb,
               const int* __restrict__ in_idx, const int* __restrict__ out_idx,
               float* __restrict__ out)
{
    constexpr int TP = 256;
    constexpr int STRIDE = 72;
    __shared__ __bf16 sA[TP * STRIDE];
    __shared__ int s_out[TP];

    const int k = blockIdx.y;
    const int tile_base = blockIdx.x * TP;
    const int t = threadIdx.x;
    const int lane = t & 63;
    const int wave = t >> 6;
    const int m16 = lane & 15;
    const int quad = lane >> 4;

    const __bf16* Wt = wtb + (size_t)k * C * C;
    bf16x8 bfrag[4][2];
#pragma unroll
    for (int nt = 0; nt < 4; ++nt)
#pragma unroll
        for (int kc = 0; kc < 2; ++kc)
            bfrag[nt][kc] = *(const bf16x8*)(Wt + (nt * 16 + m16) * C + kc * 32 + quad * 8);

    {
        const int pair = tile_base + t;
        s_out[t] = (pair < PPK) ? out_idx[(size_t)k * PPK + pair] : 0;
    }

    const int c8 = t & 7;
    const int r0 = t >> 3;
#pragma unroll
    for (int it = 0; it < 8; ++it) {
        const int r = r0 + it * 32;
        const int pair = tile_base + r;
        const int row = (pair < PPK) ? in_idx[(size_t)k * PPK + pair] : 0;
        const float4 v = *(const float4*)(featb + (size_t)row * C + c8 * 8);
        *(float4*)(sA + r * STRIDE + c8 * 8) = v;
    }
    __syncthreads();

    f32x4 acc[4][4] = {};
    const int mbase = wave * 64;
#pragma unroll
    for (int kc = 0; kc < 2; ++kc) {
        bf16x8 afrag[4];
#pragma unroll
        for (int mt = 0; mt < 4; ++mt)
            afrag[mt] = *(const bf16x8*)(sA + (mbase + mt * 16 + m16) * STRIDE + kc * 32 + quad * 8);
#pragma unroll
        for (int nt = 0; nt < 4; ++nt)
#pragma unroll
            for (int mt = 0; mt < 4; ++mt)
                acc[mt][nt] = __builtin_amdgcn_mfma_f32_16x16x32_bf16(
                    afrag[mt], bfrag[nt][kc], acc[mt][nt], 0, 0, 0);
    }

#pragma unroll
    for (int mt = 0; mt < 4; ++mt) {
#pragma unroll
        for (int reg = 0; reg < 4; ++reg) {
            const int r = mbase + mt * 16 + quad * 4 + reg;
            const int pair = tile_base + r;
            if (pair < PPK) {
                const int o = s_out[r];
                float* orow = out + (size_t)o * C + m16;
#pragma unroll
                for (int nt = 0; nt < 4; ++nt)
                    unsafeAtomicAdd(orow + nt * 16, acc[mt][nt][reg]);
            }
        }
    }
}

__global__ __launch_bounds__(256)
void stats_kernel(const float* __restrict__ out,
                  float* __restrict__ stats,
                  int rows_per_block)
{
    __shared__ float ssum[256];
    __shared__ float ssq[256];
    const int c   = threadIdx.x & 63;
    const int sub = threadIdx.x >> 6;
    const int row0 = blockIdx.x * rows_per_block;
    const int row1 = min(row0 + rows_per_block, N_VOX);
    float s = 0.f, q = 0.f;
    for (int r = row0 + sub; r < row1; r += 4) {
        const float v = out[(size_t)r * C + c];
        s += v;
        q += v * v;
    }
    ssum[threadIdx.x] = s;
    ssq[threadIdx.x]  = q;
    __syncthreads();
    if (sub == 0) {
        s = ssum[c] + ssum[64 + c] + ssum[128 + c] + ssum[192 + c];
        q = ssq[c]  + ssq[64 + c]  + ssq[128 + c]  + ssq[192 + c];
        unsafeAtomicAdd(&stats[c], s);
        unsafeAtomicAdd(&stats[64 + c], q);
    }
}

// ---------------------------------------------------------------------------
// Norm with finalize fused: per-thread scale/shift from stats (4 rsqrt).
// ---------------------------------------------------------------------------
__global__ __launch_bounds__(256)
void norm_kernel(float* __restrict__ out, const float* __restrict__ stats,
                 const float* __restrict__ gamma, const float* __restrict__ beta)
{
    const size_t total4 = (size_t)N_VOX * C / 4;
    const size_t idx = (size_t)blockIdx.x * blockDim.x + threadIdx.x;
    if (idx >= total4) return;
    const int c4 = (int)(idx & 15);
    const float inv_n = 1.0f / (float)N_VOX;
    const float4 sm = ((const float4*)stats)[c4];
    const float4 sq = ((const float4*)(stats + 64))[c4];
    const float4 g  = ((const float4*)gamma)[c4];
    const float4 be = ((const float4*)beta)[c4];
    float4 v = ((const float4*)out)[idx];
    {
        const float mean = sm.x * inv_n;
        const float sc = rsqrtf(sq.x * inv_n - mean * mean + BN_EPS) * g.x;
        v.x = fmaxf(v.x * sc + (be.x - mean * sc), 0.f);
    }
    {
        const float mean = sm.y * inv_n;
        const float sc = rsqrtf(sq.y * inv_n - mean * mean + BN_EPS) * g.y;
        v.y = fmaxf(v.y * sc + (be.y - mean * sc), 0.f);
    }
    {
        const float mean = sm.z * inv_n;
        const float sc = rsqrtf(sq.z * inv_n - mean * mean + BN_EPS) * g.z;
        v.z = fmaxf(v.z * sc + (be.z - mean * sc), 0.f);
    }
    {
        const float mean = sm.w * inv_n;
        const float sc = rsqrtf(sq.w * inv_n - mean * mean + BN_EPS) * g.w;
        v.w = fmaxf(v.w * sc + (be.w - mean * sc), 0.f);
    }
    ((float4*)out)[idx] = v;
}

static inline size_t align_up(size_t x) { return (x + 255) & ~(size_t)255; }

extern "C" void kernel_launch(void* const* d_in, const int* in_sizes, int n_in,
                              void* d_out, int out_size, void* d_ws, size_t ws_size,
                              hipStream_t stream)
{
    const float* features = (const float*)d_in[0];
    const float* weight   = (const float*)d_in[1];
    // d_in[2] = bias: cancels under BN, unused.
    const float* gamma    = (const float*)d_in[3];
    const float* beta     = (const float*)d_in[4];
    const int*   in_idx   = (const int*)d_in[5];
    const int*   out_idx  = (const int*)d_in[6];
    float* out = (float*)d_out;

    // workspace layout (identical footprint to the proven round-4 version)
    char* base = (char*)d_ws;
    size_t off = 0;
    __bf16* featb = (__bf16*)(base + off); off += align_up((size_t)N_VOX * C * 2);
    __bf16* wtb   = (__bf16*)(base + off); off += align_up((size_t)KOFF * C * C * 2);
    float*  stats = (float*)(base + off);  off += align_up(128 * 4);
    float*  ss    = (float*)(base + off);  off += align_up(128 * 4);
    unsigned* counts  = (unsigned*)(base + off); off += align_up((size_t)N_VOX * 4);
    unsigned* offsets = (unsigned*)(base + off); off += align_up((size_t)N_VOX * 4);
    unsigned* bsums   = (unsigned*)(base + off); off += align_up(256 * 4);
    const size_t fixed = off;
    (void)ss;

    // per k-offset per chunk: rank u32[PPK] + partial bf16[PPK][64] = 132 B/pair
    int g_cap = 0;
    if (ws_size > fixed)
        g_cap = (int)((ws_size - fixed) / ((size_t)PPK * 132));
    if (g_cap > KOFF) g_cap = KOFF;

    const bool fused = (g_cap >= 2);

    const size_t total4 = (size_t)N_VOX * C / 4;
    convert_features<<<(int)((total4 + 255) / 256), 256, 0, stream>>>(features, featb);
    convert_weight<<<KOFF, 256, 0, stream>>>(weight, wtb,
                                             fused ? counts : nullptr, stats);

    if (fused) {
        // sorted-partial path: invert rulebook per chunk, no f32 atomics.
        const int G = (KOFF + g_cap - 1) / g_cap;
        const int gmax = (KOFF + G - 1) / G;
        unsigned* rank = (unsigned*)(base + off);
        __bf16* partial = (__bf16*)(base + off + align_up((size_t)gmax * PPK * 4));
        const int gbase_sz = KOFF / G, rem = KOFF % G;
        int k0 = 0;
        for (int ci = 0; ci < G; ++ci) {
            const int g = gbase_sz + (ci < rem ? 1 : 0);
            const int np = g * PPK;
            hist_kernel<<<(np + 255) / 256, 256, 0, stream>>>(out_idx, counts, rank, k0, np);
            scan1<<<(N_VOX + 1023) / 1024, 256, 0, stream>>>(counts, offsets, bsums);
            scan23<<<(N_VOX + 255) / 256, 256, 0, stream>>>(offsets, bsums);
            dim3 cgrid((PPK + 255) / 256, g);
            conv_scatter<<<cgrid, 256, 0, stream>>>(featb, wtb, in_idx, out_idx,
                                                    rank, offsets, partial, k0);
            reduce_kernel<<<2048, 256, 0, stream>>>(partial, offsets, out, stats,
                                                    ci == 0 ? 1 : 0,
                                                    ci == G - 1 ? 1 : 0,
                                                    (unsigned)np);
            k0 += g;
        }
    } else {
        // fallback: proven atomic path
        hipMemsetAsync(stats, 0, 128 * sizeof(float), stream);
        hipMemsetAsync(out, 0, (size_t)N_VOX * C * sizeof(float), stream);
        dim3 cgrid((PPK + 255) / 256, KOFF);
        conv_mfma<<<cgrid, 256, 0, stream>>>(featb, wtb, in_idx, out_idx, out);
        const int rpb = (N_VOX + 511) / 512;
        stats_kernel<<<512, 256, 0, stream>>>(out, stats, rpb);
    }

    norm_kernel<<<(int)((total4 + 255) / 256), 256, 0, stream>>>(out, stats, gamma, beta);
}